// Round 4
// baseline (760.321 us; speedup 1.0000x reference)
//
#include <hip/hip_runtime.h>
#include <hip/hip_bf16.h>
#include <math.h>

typedef __attribute__((ext_vector_type(4))) float f32x4;
typedef __attribute__((ext_vector_type(8))) short s16x8;

#define LOG2E 1.4426950408889634f
#define LN2f  0.6931471805599453f
#define INV_E 0.36787944117144233f

__device__ __forceinline__ short bfc(float x) {
  unsigned u = __float_as_uint(x);
  unsigned r = u + 0x7fffu + ((u >> 16) & 1u);   // RNE to bf16
  return (short)(r >> 16);
}

__device__ __forceinline__ unsigned pk2(float x, float y) {
  union { __hip_bfloat162 h; unsigned u; } c;
  c.h = __float22bfloat162_rn(make_float2(x, y));  // v_cvt_pk_bf16_f32
  return c.u;
}

__device__ __forceinline__ float rdlane(float v, int lane) {
  return __int_as_float(__builtin_amdgcn_readlane(__float_as_int(v), lane));
}

__device__ __forceinline__ float pick9(int j, float a0, float a1, float a2,
                                       float a3, float a4, float a5, float a6,
                                       float a7, float a8) {
  float v = a0;
  if (j == 1) v = a1;
  if (j == 2) v = a2;
  if (j == 3) v = a3;
  if (j == 4) v = a4;
  if (j == 5) v = a5;
  if (j == 6) v = a6;
  if (j == 7) v = a7;
  if (j == 8) v = a8;
  return v;
}

// ---------------------------------------------------------------------------
// Kernel 0: W (V x D fp32) -> Wb (64 x D bf16), rows >= V zero-filled.
// Also zeroes the producer/consumer flags (kernel-boundary release makes the
// zeros visible to the fused kernel; replaces the separate hipMemsetAsync).
// ---------------------------------------------------------------------------
__global__ void conv_w(const float* __restrict__ W, short* __restrict__ Wb,
                       int V, int D, int* __restrict__ flags, int nflags) {
  int idx = blockIdx.x * blockDim.x + threadIdx.x;
  if (idx < nflags) flags[idx] = 0;
  if (idx >= 64 * D) return;
  int row = idx / D, col = idx - row * D;
  Wb[idx] = (row < V) ? bfc(W[(size_t)row * D + col]) : (short)0;
}

// ---------------------------------------------------------------------------
// Fused kernel v4:
//   blocks [0, B)           : star-CTC DP consumer (1 wave; waves 1-3 return)
//   blocks [B, B+B*CPB)     : ONE-SHOT producers, one 128-row tile each
//                             (t-major: b=j%B, c=j/B). All co-resident ->
//                             max TLP (8 waves/CU, r1-proven 156us span).
// Producer k-loop is a 4-DEEP software pipeline (4 static register stage-
// sets, manually unrolled so all indexing is compile-time): 24-32 load-
// instructions in flight per wave vs 8 in v3. v3 counters proved the
// phase is outstanding-transaction-bound (all pipes <7% busy, 490 GB/s),
// and r1 showed throughput scales with in-flight count.
// Producer pre-gathers emissions into DP layout:
//   ptg[row][lane] = float4(e1,e3,e5,e7); sk[row] = float2(star~, ln s)
// Sync: per-(b,c) flag RELEASE; consumer polls RELAXED agent-scope + one
// acquire fence per chunk crossing.
// ---------------------------------------------------------------------------
__global__ __launch_bounds__(256, 2) void fused_gemm_star(
    const float* __restrict__ feat, const short* __restrict__ Wb,
    const float* __restrict__ bias, float* __restrict__ ptg,
    float* __restrict__ skb, int* __restrict__ flags,
    const int* __restrict__ targets, const int* __restrict__ in_len,
    const int* __restrict__ tgt_len, float* __restrict__ partial,
    int nrows, int D, int V, int T, int S, int B, int CPB) {

  __shared__ float gbuf[4][4][64];   // [wave][row-in-iter][class]

  if ((int)blockIdx.x >= B) {
    // ===================== one-shot producer (one tile) ===================
    const int j = blockIdx.x - B;
    const int c = j / B;
    const int b = j - c * B;
    const int tc0 = c * 128;
    const int rlen = (T - tc0 < 128) ? (T - tc0) : 128;
    const int rowlim = b * T + tc0 + rlen;

    const int lane = threadIdx.x & 63;
    const int wave = threadIdx.x >> 6;
    const int m_lo = lane & 15;
    const int q = lane >> 4;
    const size_t bstr = (size_t)16 * D;
    const int rowbase = b * T + tc0 + wave * 32;

    // DP-lane labels for this batch (gather indices)
    const int* tg = targets + (size_t)b * S;
    const int l0 = lane * 4;
    const int g1 = (l0 < S) ? tg[l0] : 0;
    const int g3 = (l0 + 1 < S) ? tg[l0 + 1] : 0;
    const int g5 = (l0 + 2 < S) ? tg[l0 + 2] : 0;
    const int g7 = (l0 + 3 < S) ? tg[l0 + 3] : 0;

    int arow0 = rowbase + m_lo;
    int arow1 = rowbase + 16 + m_lo;
    if (arow0 >= nrows) arow0 = nrows - 1;       // clamp loads; stores guarded
    if (arow1 >= nrows) arow1 = nrows - 1;
    const float* A0base = feat + (size_t)arow0 * D + q * 8;
    const float* A1base = feat + (size_t)arow1 * D + q * 8;
    const short* Bbase = Wb + (size_t)m_lo * D + q * 8;

    f32x4 acc[2][4];
    #pragma unroll
    for (int g = 0; g < 2; ++g)
      #pragma unroll
      for (int ni = 0; ni < 4; ++ni) acc[g][ni] = (f32x4){0.f, 0.f, 0.f, 0.f};

    // 4 static register stage-sets (compile-time indexed — rule #20)
#define DECLS(s) float4 al0_##s, ah0_##s, al1_##s, ah1_##s;                  \
                 s16x8 b0_##s, b1_##s, b2_##s, b3_##s
    DECLS(0); DECLS(1); DECLS(2); DECLS(3);
#undef DECLS

#define LOADS(s, kk)                                                         \
  do {                                                                       \
    const float* A0p = A0base + (kk);                                        \
    const float* A1p = A1base + (kk);                                        \
    const short* Bpp = Bbase + (kk);                                         \
    al0_##s = *(const float4*)(A0p);                                         \
    ah0_##s = *(const float4*)(A0p + 4);                                     \
    al1_##s = *(const float4*)(A1p);                                         \
    ah1_##s = *(const float4*)(A1p + 4);                                     \
    b0_##s = *(const s16x8*)(Bpp);                                           \
    b1_##s = *(const s16x8*)(Bpp + bstr);                                    \
    b2_##s = *(const s16x8*)(Bpp + 2 * bstr);                                \
    b3_##s = *(const s16x8*)(Bpp + 3 * bstr);                                \
  } while (0)

#define COMPUTE(s)                                                           \
  do {                                                                       \
    union { s16x8 v; unsigned u[4]; } av0, av1;                              \
    av0.u[0] = pk2(al0_##s.x, al0_##s.y);                                    \
    av0.u[1] = pk2(al0_##s.z, al0_##s.w);                                    \
    av0.u[2] = pk2(ah0_##s.x, ah0_##s.y);                                    \
    av0.u[3] = pk2(ah0_##s.z, ah0_##s.w);                                    \
    av1.u[0] = pk2(al1_##s.x, al1_##s.y);                                    \
    av1.u[1] = pk2(al1_##s.z, al1_##s.w);                                    \
    av1.u[2] = pk2(ah1_##s.x, ah1_##s.y);                                    \
    av1.u[3] = pk2(ah1_##s.z, ah1_##s.w);                                    \
    acc[0][0] = __builtin_amdgcn_mfma_f32_16x16x32_bf16(av0.v, b0_##s, acc[0][0], 0, 0, 0); \
    acc[0][1] = __builtin_amdgcn_mfma_f32_16x16x32_bf16(av0.v, b1_##s, acc[0][1], 0, 0, 0); \
    acc[0][2] = __builtin_amdgcn_mfma_f32_16x16x32_bf16(av0.v, b2_##s, acc[0][2], 0, 0, 0); \
    acc[0][3] = __builtin_amdgcn_mfma_f32_16x16x32_bf16(av0.v, b3_##s, acc[0][3], 0, 0, 0); \
    acc[1][0] = __builtin_amdgcn_mfma_f32_16x16x32_bf16(av1.v, b0_##s, acc[1][0], 0, 0, 0); \
    acc[1][1] = __builtin_amdgcn_mfma_f32_16x16x32_bf16(av1.v, b1_##s, acc[1][1], 0, 0, 0); \
    acc[1][2] = __builtin_amdgcn_mfma_f32_16x16x32_bf16(av1.v, b2_##s, acc[1][2], 0, 0, 0); \
    acc[1][3] = __builtin_amdgcn_mfma_f32_16x16x32_bf16(av1.v, b3_##s, acc[1][3], 0, 0, 0); \
  } while (0)

    // 4-deep pipeline prologue: k = 0, 32, 64, 96 in flight
    LOADS(0, 0); LOADS(1, 32); LOADS(2, 64); LOADS(3, 96);
    // main loop: D assumed multiple of 128 (D=1024 here); dummy reloads on
    // the final round keep control flow uniform (in-bounds, discarded).
    for (int k0 = 0; k0 < D; k0 += 128) {
      { COMPUTE(0); int kp = k0 + 128; if (kp >= D) kp = 0;  LOADS(0, kp); }
      { COMPUTE(1); int kp = k0 + 160; if (kp >= D) kp = 32; LOADS(1, kp); }
      { COMPUTE(2); int kp = k0 + 192; if (kp >= D) kp = 64; LOADS(2, kp); }
      { COMPUTE(3); int kp = k0 + 224; if (kp >= D) kp = 96; LOADS(3, kp); }
    }
#undef LOADS
#undef COMPUTE

    float bias_v[4];
    #pragma unroll
    for (int ni = 0; ni < 4; ++ni) {
      int col = ni * 16 + m_lo;
      bias_v[ni] = (col < V) ? bias[col] : 0.f;
    }

    // C/D layout: col = lane&15, row = (lane>>4)*4 + reg   [m89-verified]
    #pragma unroll
    for (int g = 0; g < 2; ++g) {
      #pragma unroll
      for (int r = 0; r < 4; ++r) {
        float lg[4];
        #pragma unroll
        for (int ni = 0; ni < 4; ++ni) {
          int col = ni * 16 + m_lo;
          lg[ni] = (col < V) ? (acc[g][ni][r] + bias_v[ni]) : -1e30f;
        }
        float m = fmaxf(fmaxf(lg[0], lg[1]), fmaxf(lg[2], lg[3]));
        #pragma unroll
        for (int off = 1; off < 16; off <<= 1) m = fmaxf(m, __shfl_xor(m, off));
        float p[4];
        #pragma unroll
        for (int ni = 0; ni < 4; ++ni) p[ni] = exp2f((lg[ni] - m) * LOG2E);
        float s = (p[0] + p[1]) + (p[2] + p[3]);
        #pragma unroll
        for (int off = 1; off < 16; off <<= 1) s += __shfl_xor(s, off);

        // stage the 4 rows of this (g,r) iter into LDS, class-indexed
        #pragma unroll
        for (int ni = 0; ni < 4; ++ni)
          gbuf[wave][q][ni * 16 + m_lo] = p[ni];

        // gather + store DP-ready rows (wave-internal DS ordering)
        #pragma unroll
        for (int rr = 0; rr < 4; ++rr) {
          int grow = rowbase + g * 16 + rr * 4 + r;
          if (grow < rowlim) {
            float srow = rdlane(s, rr * 16);
            float4 ev;
            ev.x = gbuf[wave][rr][g1];
            ev.y = gbuf[wave][rr][g3];
            ev.z = gbuf[wave][rr][g5];
            ev.w = gbuf[wave][rr][g7];
            *(float4*)(ptg + ((size_t)grow * 64 + lane) * 4) = ev;
            if (lane == 0) {
              float2 skv;
              skv.x = srow * INV_E;      // star~ emission
              skv.y = logf(srow);       // K_t (ln units)
              *(float2*)(skb + (size_t)grow * 2) = skv;
            }
          }
        }
      }
    }

    __syncthreads();                 // all 4 waves' stores issued+drained
    if (threadIdx.x == 0)
      __hip_atomic_store(&flags[b * CPB + c], 1, __ATOMIC_RELEASE,
                         __HIP_MEMORY_SCOPE_AGENT);
    return;
  }

  // ================= consumer: star-CTC DP (1 wave / sequence) =============
  if (threadIdx.x >= 64) return;
  const int n = blockIdx.x;
  const int lane = threadIdx.x;
  const int len = in_len[n];
  const int tl = tgt_len[n];
  const int* tg = targets + (size_t)n * S;
  const int* fl = flags + n * CPB;
  const float* prow = ptg + (size_t)n * T * 256;
  const float* srow = skb + (size_t)n * T * 2;

  int cdone = -1;
#define WAITC(cc)                                                            \
  do {                                                                       \
    int _c = (cc);                                                           \
    if (cdone < _c) {                                                        \
      while (cdone < _c) {                                                   \
        if (__hip_atomic_load((int*)&fl[cdone + 1], __ATOMIC_RELAXED,        \
                              __HIP_MEMORY_SCOPE_AGENT))                     \
          ++cdone;                                                           \
        else                                                                 \
          __builtin_amdgcn_s_sleep(8);                                       \
      }                                                                      \
      __builtin_amdgcn_fence(__ATOMIC_ACQUIRE, "agent");                     \
    }                                                                        \
  } while (0)

  const int s0 = lane * 4;
  int lab1 = (s0     < S) ? tg[s0]     : 0;
  int lab3 = (s0 + 1 < S) ? tg[s0 + 1] : 0;
  int lab5 = (s0 + 2 < S) ? tg[s0 + 2] : 0;
  int lab7 = (s0 + 3 < S) ? tg[s0 + 3] : 0;
  int labm1 = __shfl_up(lab7, 1);                // label of state 8k-1
  int labm3 = __shfl_up(lab5, 1);                // label of state 8k-3
  const bool sk1 = (lane > 0) && (lab1 != labm1);
  const bool sk3 = (lab3 != lab1);
  const bool sk5 = (lab5 != lab3);
  const bool sk7 = (lab7 != lab5);
  const bool skm1 = (labm1 != labm3);

  float a0 = 0, a1 = 0, a2 = 0, a3 = 0, a4 = 0, a5 = 0, a6 = 0, a7 = 0, a8 = 0;
  float m1 = 0.f, m2 = 0.f, m3 = 0.f;
  int eps = 0, eL = 0;
  bool act = (lane == 0);

#define PTGL(t) (*(const float4*)(prow +                                     \
    ((size_t)(((t) < len) ? (t) : (len - 1)) * 256 + lane * 4)))
#define SKLL(t) (*(const float2*)(srow +                                     \
    ((size_t)(((t) < len) ? (t) : (len - 1)) * 2)))

  WAITC(0);                                      // rows 0..8 live in chunk 0

  // t = 0
  float4 r0 = PTGL(0);
  float2 k0v = SKLL(0);
  if (lane == 0) { a0 = k0v.x; a1 = r0.x; }      // star~, e1 = p[tg[0]]
  float ksum = k0v.y;                            // uniform across lanes

  // prefetch ring: rows 1..8 (emissions + star/K)
  float4 rr0 = PTGL(1), rr1 = PTGL(2), rr2 = PTGL(3), rr3 = PTGL(4);
  float4 rr4 = PTGL(5), rr5 = PTGL(6), rr6 = PTGL(7), rr7 = PTGL(8);
  float2 kr0 = SKLL(1), kr1 = SKLL(2), kr2 = SKLL(3), kr3 = SKLL(4);
  float2 kr4 = SKLL(5), kr5 = SKLL(6), kr6 = SKLL(7), kr7 = SKLL(8);

  float em1a = __shfl_up(rr0.w, 1);              // e_{8k-1} for first pair

#define RENORM()                                                             \
  do {                                                                       \
    float mx = fmaxf(fmaxf(fmaxf(a0, a1), fmaxf(a2, a3)),                    \
                     fmaxf(fmaxf(a4, a5), fmaxf(a6, a7)));                   \
    mx = fmaxf(mx, a8);                                                      \
    int e = (int)((__float_as_uint(mx) >> 23) & 255) - 126;                  \
    e = (act && mx > 0.f) ? e : 0;                                           \
    a0 = ldexpf(a0, -e); a1 = ldexpf(a1, -e); a2 = ldexpf(a2, -e);           \
    a3 = ldexpf(a3, -e); a4 = ldexpf(a4, -e); a5 = ldexpf(a5, -e);           \
    a6 = ldexpf(a6, -e); a7 = ldexpf(a7, -e); a8 = ldexpf(a8, -e);           \
    eps += e;                                                                \
  } while (0)

#define PAIR(EC0, EC1, KC0, KC1, NX, P0, P1, DOREN)                          \
  do {                                                                       \
    ksum += KC0.y; ksum += KC1.y;                                            \
    if (!act) eps = eL;                                                      \
    bool inc = (lane != 0) &&                                                \
               ((m1 != 0.f) || (m2 != 0.f) || (m3 != 0.f));                  \
    int d = inc ? (eL - eps) : 0;                                            \
    if (__builtin_expect(d > 24, 0)) {            /* raise own frame */      \
      a0 = ldexpf(a0, -d); a1 = ldexpf(a1, -d); a2 = ldexpf(a2, -d);         \
      a3 = ldexpf(a3, -d); a4 = ldexpf(a4, -d); a5 = ldexpf(a5, -d);         \
      a6 = ldexpf(a6, -d); a7 = ldexpf(a7, -d); a8 = ldexpf(a8, -d);         \
      eps += d;                                   /* m stay in frame eL */   \
    } else {                                                                 \
      m1 = ldexpf(m1, d); m2 = ldexpf(m2, d); m3 = ldexpf(m3, d);            \
    }                                                                        \
    act = act || (m1 != 0.f) || (m2 != 0.f) || (m3 != 0.f);                  \
    /* sub-step 1 (in-place top-down; uses old lower states) */              \
    a8 = (a8 + a7) * KC0.x;                                                  \
    a7 = (a7 + a6 + (sk7 ? a5 : 0.f)) * EC0.w;                               \
    a6 = (a6 + a5) * KC0.x;                                                  \
    a5 = (a5 + a4 + (sk5 ? a3 : 0.f)) * EC0.z;                               \
    a4 = (a4 + a3) * KC0.x;                                                  \
    a3 = (a3 + a2 + (sk3 ? a1 : 0.f)) * EC0.y;                               \
    a2 = (a2 + a1) * KC0.x;                                                  \
    a1 = (a1 + a0 + (sk1 ? m1 : 0.f)) * EC0.x;                               \
    a0 = (a0 + m1) * KC0.x;                                                  \
    m1 = (m1 + m2 + (skm1 ? m3 : 0.f)) * em1a;                               \
    /* sub-step 2 */                                                         \
    a8 = (a8 + a7) * KC1.x;                                                  \
    a7 = (a7 + a6 + (sk7 ? a5 : 0.f)) * EC1.w;                               \
    a6 = (a6 + a5) * KC1.x;                                                  \
    a5 = (a5 + a4 + (sk5 ? a3 : 0.f)) * EC1.z;                               \
    a4 = (a4 + a3) * KC1.x;                                                  \
    a3 = (a3 + a2 + (sk3 ? a1 : 0.f)) * EC1.y;                               \
    a2 = (a2 + a1) * KC1.x;                                                  \
    a1 = (a1 + a0 + (sk1 ? m1 : 0.f)) * EC1.x;                               \
    a0 = (a0 + m1) * KC1.x;                                                  \
    EC0 = PTGL(P0); EC1 = PTGL(P1);               /* refill ring slots */    \
    KC0 = SKLL(P0); KC1 = SKLL(P1);                                          \
    if (DOREN) RENORM();                                                     \
    em1a = __shfl_up(NX.w, 1);                    /* next pair's e_{8k-1} */ \
    /* boundary shuffles (states 8k-3..8k-1 + frame) */                      \
    m3 = __shfl_up(a5, 1); m2 = __shfl_up(a6, 1); m1 = __shfl_up(a7, 1);     \
    eL = __shfl_up(eps, 1);                                                  \
    if (lane == 0) { m1 = 0.f; m2 = 0.f; m3 = 0.f; }                         \
  } while (0)

  int t0 = 1;
  for (; t0 + 8 <= len; t0 += 8) {
    int tmax = t0 + 15;
    if (tmax > len - 1) tmax = len - 1;
    WAITC(tmax >> 7);                            // gate ring refills t0+8..+15
    PAIR(rr0, rr1, kr0, kr1, rr2, t0 + 8,  t0 + 9,  false);
    PAIR(rr2, rr3, kr2, kr3, rr4, t0 + 10, t0 + 11, false);
    PAIR(rr4, rr5, kr4, kr5, rr6, t0 + 12, t0 + 13, false);
    PAIR(rr6, rr7, kr6, kr7, rr0, t0 + 14, t0 + 15, true);  // t0+7==0 mod 8
  }

  WAITC((len - 1) >> 7);                         // cover tail reads

  // tail: <= 7 single steps (m1/eL re-shuffled each step; no em1 needed)
  for (int t = t0; t < len; ++t) {
    float4 cv = PTGL(t);
    float2 kc = SKLL(t);
    ksum += kc.y;
    if (!act) eps = eL;
    bool inc = (lane != 0) && (m1 != 0.f);
    int d = inc ? (eL - eps) : 0;
    float m1s;
    if (__builtin_expect(d > 24, 0)) {
      a0 = ldexpf(a0, -d); a1 = ldexpf(a1, -d); a2 = ldexpf(a2, -d);
      a3 = ldexpf(a3, -d); a4 = ldexpf(a4, -d); a5 = ldexpf(a5, -d);
      a6 = ldexpf(a6, -d); a7 = ldexpf(a7, -d); a8 = ldexpf(a8, -d);
      eps += d; m1s = m1;
    } else {
      m1s = inc ? ldexpf(m1, d) : 0.f;
    }
    act = act || (m1s != 0.f);
    a8 = (a8 + a7) * kc.x;
    a7 = (a7 + a6 + (sk7 ? a5 : 0.f)) * cv.w;
    a6 = (a6 + a5) * kc.x;
    a5 = (a5 + a4 + (sk5 ? a3 : 0.f)) * cv.z;
    a4 = (a4 + a3) * kc.x;
    a3 = (a3 + a2 + (sk3 ? a1 : 0.f)) * cv.y;
    a2 = (a2 + a1) * kc.x;
    a1 = (a1 + a0 + (sk1 ? m1s : 0.f)) * cv.x;
    a0 = (a0 + m1s) * kc.x;
    if ((t & 7) == 0) RENORM();
    m1 = __shfl_up(a7, 1);
    eL = __shfl_up(eps, 1);
    if (lane == 0) m1 = 0.f;
  }

  // final reduce — all cross-lane via shfl (no LDS / no barrier)
  int last = 2 * tl;
  int kx = last >> 3, jx = last & 7;
  if (kx > 63) { kx = 63; jx = last - 504; }     // state 512 -> lane63 a8
  int ky = (last - 1) >> 3, jy = (last - 1) & 7;
  float vx = pick9(jx, a0, a1, a2, a3, a4, a5, a6, a7, a8);
  float vy = pick9(jy, a0, a1, a2, a3, a4, a5, a6, a7, a8);
  float sx = __shfl(vx, kx); int ex = __shfl(eps, kx);
  float sy = __shfl(vy, ky); int ey = __shfl(eps, ky);
  if (lane == 0) {
    int em = (ex > ey) ? ex : ey;
    float v = ldexpf(sx, ex - em) + ldexpf(sy, ey - em);
    float score = logf(v) + (float)em * LN2f - ksum;
    partial[n] = -score / (float)tl;
  }
#undef WAITC
#undef PTGL
#undef SKLL
#undef RENORM
#undef PAIR
}

// ---------------------------------------------------------------------------
// Kernel 3: mean over batch
// ---------------------------------------------------------------------------
__global__ void reduce_mean(const float* __restrict__ partial,
                            float* __restrict__ out, int B) {
  float v = 0.f;
  for (int i = threadIdx.x; i < B; i += 64) v += partial[i];
  #pragma unroll
  for (int off = 32; off > 0; off >>= 1) v += __shfl_down(v, off, 64);
  if (threadIdx.x == 0) out[0] = v / (float)B;
}

extern "C" void kernel_launch(void* const* d_in, const int* in_sizes, int n_in,
                              void* d_out, int out_size, void* d_ws, size_t ws_size,
                              hipStream_t stream) {
  const float* feat = (const float*)d_in[0];
  const float* W = (const float*)d_in[1];
  const float* bias = (const float*)d_in[2];
  const int* targets = (const int*)d_in[3];
  const int* in_len = (const int*)d_in[4];
  const int* tgt_len = (const int*)d_in[5];
  float* out = (float*)d_out;

  const int V = in_sizes[2];
  const int D = in_sizes[1] / V;
  const int B = in_sizes[4];
  const int T = in_sizes[0] / (B * D);
  const int S = in_sizes[3] / B;
  const int nrows = B * T;

  float* ptg = (float*)d_ws;                        // nrows*256 fp32 (64 MB)
  float* skb = ptg + (size_t)nrows * 256;           // nrows*2 fp32
  float* partial = skb + (size_t)nrows * 2;         // B fp32
  short* Wb = (short*)(partial + B);                // 64*D bf16
  const int CPB = (T + 127) / 128;                  // time-chunks per batch
  int* flags = (int*)((char*)Wb + (size_t)64 * D * sizeof(short));  // B*CPB

  conv_w<<<(64 * D + 255) / 256, 256, 0, stream>>>(W, Wb, V, D,
                                                   flags, B * CPB);

  // grid = B consumers + B*CPB one-shot producers (all ~co-resident,
  // 8 waves/CU; overflow blocks are the last-needed c=15 chunks).
  const int NTILES = B * CPB;
  fused_gemm_star<<<dim3(B + NTILES), 256, 0, stream>>>(
      feat, Wb, bias, ptg, skb, flags, targets, in_len, tgt_len, partial,
      nrows, D, V, T, S, B, CPB);

  reduce_mean<<<1, 64, 0, stream>>>(partial, out, B);
}